// Round 8
// baseline (8493.655 us; speedup 1.0000x reference)
//
#include <hip/hip_runtime.h>
#include <math.h>

#define TT_ 128
#define DD 64
#define HH 256
#define BB 16      // batch rows per block (MFMA M-tile)
#define NBLK 64    // 1024/16
#define NTHR 1024  // 16 waves, 1 N-tile (16 cols) per wave

// f32 LDS stride (elements): 260*4B = 1040B (odd multiple of 16B)
#define SA 260
// bf16 plane strides (elements): 264*2B = 528B, 72*2B = 144B (odd multiples of 16B)
#define SB 264
#define SXB 72

typedef short bf16x8 __attribute__((ext_vector_type(8)));
typedef float f32x4 __attribute__((ext_vector_type(4)));
typedef unsigned int uint;
typedef unsigned short ushort;

// ---- fragment-linear packed weights (bf16 hi/lo pairs), written by prep ----
// frag elem (tile t, oct o): W[t*16 + l%16][o*32 + (l/16)*8 + j], hi at +0, lo at +512
__device__ ushort g_W1p[16 * 8 * 2 * 512];    // W1  (256x256): t*8192 + o*1024
__device__ ushort g_W2p[16 * 8 * 2 * 512];    // W2  (256x256)
__device__ ushort g_Wrzp[32 * 10 * 2 * 512];  // Whh rows 0..511 (o<8) | Wih rows 0..511 (o=8,9): t*10240 + o*1024
__device__ ushort g_Whnp[16 * 8 * 2 * 512];   // Whh rows 512..767
__device__ ushort g_Winp[16 * 2 * 512];       // Wih rows 512..767 (hi only): t*1024 + o*512

__device__ __forceinline__ ushort bf16_rne(float f) {
  uint u = __builtin_bit_cast(uint, f);
  return (ushort)((u + 0x7fffu + ((u >> 16) & 1u)) >> 16);
}
__device__ __forceinline__ float bf16_f32(ushort h) {
  uint u = ((uint)h) << 16;
  return __builtin_bit_cast(float, u);
}
// truncation split: hi+lo reproduces f to ~2^-17 rel
__device__ __forceinline__ void hl_split(float f, ushort& hi, ushort& lo) {
  const uint u = __builtin_bit_cast(uint, f);
  hi = (ushort)(u >> 16);
  const float fh = __builtin_bit_cast(float, u & 0xffff0000u);
  lo = (ushort)(__builtin_bit_cast(uint, f - fh) >> 16);
}

__global__ __launch_bounds__(256) void prep(
    const float* __restrict__ W1, const float* __restrict__ W2,
    const float* __restrict__ Wih, const float* __restrict__ Whh)
{
  const int s = blockIdx.x * 256 + threadIdx.x;
  const int S1 = 16 * 8 * 512;
  const int S2 = S1 + 16 * 8 * 512;
  const int S3 = S2 + 32 * 10 * 512;
  const int S4 = S3 + 16 * 8 * 512;
  const int S5 = S4 + 16 * 2 * 512;
  if (s >= S5) return;

  if (s < S2) {  // W1 / W2
    const int r = (s < S1) ? s : s - S1;
    const int t = r / (8 * 512);
    const int o = (r / 512) & 7;
    const int pos = r & 511;
    const int l = pos >> 3, j = pos & 7;
    const int n = t * 16 + (l & 15);
    const int k = o * 32 + (l >> 4) * 8 + j;
    const float w = (s < S1) ? W1[n * HH + k] : W2[n * HH + k];
    ushort hi = bf16_rne(w);
    ushort lo = bf16_rne(w - bf16_f32(hi));
    ushort* dst = (s < S1) ? g_W1p : g_W2p;
    dst[((t * 8 + o) * 2) * 512 + pos] = hi;
    dst[((t * 8 + o) * 2 + 1) * 512 + pos] = lo;
  } else if (s < S3) {  // Wrz
    const int r = s - S2;
    const int t = r / (10 * 512);
    const int o = (r / 512) % 10;
    const int pos = r & 511;
    const int l = pos >> 3, j = pos & 7;
    const int n = t * 16 + (l & 15);
    float w;
    if (o < 8) w = Whh[n * HH + o * 32 + (l >> 4) * 8 + j];
    else       w = Wih[n * DD + (o - 8) * 32 + (l >> 4) * 8 + j];
    ushort hi = bf16_rne(w);
    ushort lo = bf16_rne(w - bf16_f32(hi));
    g_Wrzp[((t * 10 + o) * 2) * 512 + pos] = hi;
    g_Wrzp[((t * 10 + o) * 2 + 1) * 512 + pos] = lo;
  } else if (s < S4) {  // Whn
    const int r = s - S3;
    const int t = r / (8 * 512);
    const int o = (r / 512) & 7;
    const int pos = r & 511;
    const int l = pos >> 3, j = pos & 7;
    const int n = 512 + t * 16 + (l & 15);
    const float w = Whh[n * HH + o * 32 + (l >> 4) * 8 + j];
    ushort hi = bf16_rne(w);
    ushort lo = bf16_rne(w - bf16_f32(hi));
    g_Whnp[((t * 8 + o) * 2) * 512 + pos] = hi;
    g_Whnp[((t * 8 + o) * 2 + 1) * 512 + pos] = lo;
  } else {  // Win (hi only)
    const int r = s - S4;
    const int t = r / (2 * 512);
    const int o = (r / 512) & 1;
    const int pos = r & 511;
    const int l = pos >> 3, j = pos & 7;
    const int n = 512 + t * 16 + (l & 15);
    const float w = Wih[n * DD + o * 32 + (l >> 4) * 8 + j];
    g_Winp[(t * 2 + o) * 512 + pos] = bf16_rne(w);
  }
}

#define MFMA(A, B, C) __builtin_amdgcn_mfma_f32_16x16x32_bf16((A), (B), (C), 0, 0, 0)

// LDS-only barrier: inter-wave comm is via LDS, wait lgkm only (keeps vmcnt loads in flight)
#define LBAR() asm volatile("s_waitcnt lgkmcnt(0)\ns_barrier" ::: "memory")

// Register-liveness fence: forces all listed fragments simultaneously live,
// so the allocator can't re-roll the load burst into serial load->use chains.
// Operands must be ext_vector types (HIP float4 is a struct -> rejected by asm).
__device__ __forceinline__ void sink16(const bf16x8* W, const bf16x8* L) {
  const f32x4 w0 = __builtin_bit_cast(f32x4, W[0]), w1 = __builtin_bit_cast(f32x4, W[1]);
  const f32x4 w2 = __builtin_bit_cast(f32x4, W[2]), w3 = __builtin_bit_cast(f32x4, W[3]);
  const f32x4 w4 = __builtin_bit_cast(f32x4, W[4]), w5 = __builtin_bit_cast(f32x4, W[5]);
  const f32x4 w6 = __builtin_bit_cast(f32x4, W[6]), w7 = __builtin_bit_cast(f32x4, W[7]);
  const f32x4 l0 = __builtin_bit_cast(f32x4, L[0]), l1 = __builtin_bit_cast(f32x4, L[1]);
  const f32x4 l2 = __builtin_bit_cast(f32x4, L[2]), l3 = __builtin_bit_cast(f32x4, L[3]);
  const f32x4 l4 = __builtin_bit_cast(f32x4, L[4]), l5 = __builtin_bit_cast(f32x4, L[5]);
  const f32x4 l6 = __builtin_bit_cast(f32x4, L[6]), l7 = __builtin_bit_cast(f32x4, L[7]);
  asm volatile("" :: "v"(w0), "v"(w1), "v"(w2), "v"(w3),
                     "v"(w4), "v"(w5), "v"(w6), "v"(w7),
                     "v"(l0), "v"(l1), "v"(l2), "v"(l3),
                     "v"(l4), "v"(l5), "v"(l6), "v"(l7));
}
__device__ __forceinline__ void sink2(const bf16x8 a, const bf16x8 b) {
  const f32x4 t0 = __builtin_bit_cast(f32x4, a);
  const f32x4 t1 = __builtin_bit_cast(f32x4, b);
  asm volatile("" :: "v"(t0), "v"(t1));
}

// 1 N-tile, K=256, 3-term split accumulation.
// Burst: ALL 16 weight loads issued, fenced live, then ds_read+MFMA.
__device__ __forceinline__ f32x4 mm1(const ushort* __restrict__ Ahi,
                                     const ushort* __restrict__ Alo,
                                     const ushort* __restrict__ pack,
                                     int tile, int lane, f32x4 acc)
{
  const int aoff = (lane & 15) * SB + (lane >> 4) * 8;
  const ushort* wp = pack + (size_t)tile * 8192 + lane * 8;
  bf16x8 wh[8], wl[8];
#pragma unroll
  for (int o = 0; o < 8; ++o) {
    wh[o] = *(const bf16x8*)(wp + o * 1024);
    wl[o] = *(const bf16x8*)(wp + o * 1024 + 512);
  }
  sink16(wh, wl);
  f32x4 a0 = acc;
  f32x4 a1 = {0.f, 0.f, 0.f, 0.f};
#pragma unroll
  for (int o = 0; o < 8; ++o) {
    const bf16x8 ah = *(const bf16x8*)(Ahi + aoff + o * 32);
    const bf16x8 al = *(const bf16x8*)(Alo + aoff + o * 32);
    f32x4& ac = (o & 1) ? a1 : a0;
    ac = MFMA(ah, wh[o], ac);
    ac = MFMA(al, wh[o], ac);
    ac = MFMA(ah, wl[o], ac);
  }
  return a0 + a1;
}

// One Wrzp tile (r: tile=wv, z: tile=16+wv): K=256 h-part (3-term) + K=64 x-part (2-term)
__device__ __forceinline__ f32x4 mm_rzt(const ushort* __restrict__ Ahi,
                                        const ushort* __restrict__ Alo,
                                        const ushort* __restrict__ Xhi,
                                        const ushort* __restrict__ Xlo,
                                        int tile, int lane, f32x4 acc)
{
  const int aoff = (lane & 15) * SB + (lane >> 4) * 8;
  const int xoff = (lane & 15) * SXB + (lane >> 4) * 8;
  const ushort* p = g_Wrzp + (size_t)tile * 10240 + lane * 8;
  bf16x8 wh[8], wl[8], wx[2];
#pragma unroll
  for (int o = 0; o < 8; ++o) {
    wh[o] = *(const bf16x8*)(p + o * 1024);
    wl[o] = *(const bf16x8*)(p + o * 1024 + 512);
  }
#pragma unroll
  for (int o = 0; o < 2; ++o)
    wx[o] = *(const bf16x8*)(p + (8 + o) * 1024);
  sink16(wh, wl);
  sink2(wx[0], wx[1]);
  f32x4 a0 = acc;
  f32x4 a1 = {0.f, 0.f, 0.f, 0.f};
#pragma unroll
  for (int o = 0; o < 8; ++o) {
    const bf16x8 ah = *(const bf16x8*)(Ahi + aoff + o * 32);
    const bf16x8 al = *(const bf16x8*)(Alo + aoff + o * 32);
    f32x4& ac = (o & 1) ? a1 : a0;
    ac = MFMA(ah, wh[o], ac);
    ac = MFMA(al, wh[o], ac);
    ac = MFMA(ah, wl[o], ac);
  }
#pragma unroll
  for (int o = 0; o < 2; ++o) {
    const bf16x8 xh = *(const bf16x8*)(Xhi + xoff + o * 32);
    const bf16x8 xl = *(const bf16x8*)(Xlo + xoff + o * 32);
    f32x4& ac = (o & 1) ? a1 : a0;
    ac = MFMA(xh, wx[o], ac);
    ac = MFMA(xl, wx[o], ac);
  }
  return a0 + a1;
}

// GRU n-gate x-side: tile wv of Winp, K=64, hi-only weights, 2-term
__device__ __forceinline__ f32x4 mm_in(const ushort* __restrict__ Xhi,
                                       const ushort* __restrict__ Xlo,
                                       int wv, int lane, f32x4 acc)
{
  const int xoff = (lane & 15) * SXB + (lane >> 4) * 8;
  const ushort* pw = g_Winp + (size_t)wv * 1024 + lane * 8;
  bf16x8 w0 = *(const bf16x8*)(pw);
  bf16x8 w1 = *(const bf16x8*)(pw + 512);
  sink2(w0, w1);
  {
    const bf16x8 xh = *(const bf16x8*)(Xhi + xoff);
    const bf16x8 xl = *(const bf16x8*)(Xlo + xoff);
    acc = MFMA(xh, w0, acc);
    acc = MFMA(xl, w0, acc);
  }
  {
    const bf16x8 xh = *(const bf16x8*)(Xhi + xoff + 32);
    const bf16x8 xl = *(const bf16x8*)(Xlo + xoff + 32);
    acc = MFMA(xh, w1, acc);
    acc = MFMA(xl, w1, acc);
  }
  return acc;
}

__global__ __launch_bounds__(NTHR, 4) void odegru_kernel(
    const float* __restrict__ x, const float* __restrict__ times,
    const float* __restrict__ mask,
    const float* __restrict__ b1, const float* __restrict__ b2,
    const float* __restrict__ bih, const float* __restrict__ bhh,
    float* __restrict__ out)
{
  // f32 state
  __shared__ __align__(16) float sAh[BB * SA];    // h (full f32 state)
  __shared__ __align__(16) float sAin[BB * SA];   // h_ode / RK stage input (f32)
  // bf16 hi/lo matmul planes
  __shared__ __align__(16) ushort sAhh[BB * SB], sAhl[BB * SB];
  __shared__ __align__(16) ushort sAinh[BB * SB], sAinl[BB * SB];
  __shared__ __align__(16) ushort sUh[BB * SB], sUl[BB * SB];
  __shared__ __align__(16) ushort sXh[BB * SXB], sXl[BB * SXB];
  __shared__ __align__(16) float sM[BB * TT_];    // mask rows for this block

  const int tid = threadIdx.x;
  const int lane = tid & 63;
  const int wv = tid >> 6;     // wave 0..15, owns output col-tile wv
  const int l15 = lane & 15;
  const int lq = lane >> 4;    // 0..3
  const int b0 = blockIdx.x * BB;

  const int c = wv * 16 + l15;       // this thread's output column
  const float b1c = b1[c];
  const float b2c = b2[c];
  const float brz_r = bih[c] + bhh[c];
  const float brz_z = bih[c + 256] + bhh[c + 256];
  const float bn_i = bih[c + 512];
  const float bn_h = bhh[c + 512];

  const f32x4 Z = {0.f, 0.f, 0.f, 0.f};

  // stage mask rows once
  sM[tid] = mask[(size_t)b0 * TT_ + tid];
  sM[tid + 1024] = mask[(size_t)b0 * TT_ + tid + 1024];

  // feval: A-planes -> kv (per-thread: col c, batches lq*4+q)
  auto feval = [&](const ushort* Ahi, const ushort* Alo, f32x4& kv) {
    f32x4 a = mm1(Ahi, Alo, g_W1p, wv, lane, Z);
#pragma unroll
    for (int q = 0; q < 4; ++q) {
      const int b = lq * 4 + q;
      const float u = fmaxf(a[q] + b1c, 0.f);
      ushort hi, lo; hl_split(u, hi, lo);
      sUh[b * SB + c] = hi;
      sUl[b * SB + c] = lo;
    }
    LBAR();
    f32x4 p = mm1(sUh, sUl, g_W2p, wv, lane, Z);
    kv = p + b2c;
  };

  // sAin <- sAh + coef*v (f32) and refresh Ain planes
  auto wAin = [&](float coef, const f32x4& v) {
#pragma unroll
    for (int q = 0; q < 4; ++q) {
      const int b = lq * 4 + q;
      const float nv = sAh[b * SA + c] + coef * v[q];
      sAin[b * SA + c] = nv;
      ushort hi, lo; hl_split(nv, hi, lo);
      sAinh[b * SB + c] = hi;
      sAinl[b * SB + c] = lo;
    }
  };

  for (int t = 0; t < TT_; ++t) {
    // stage x[:, t, :] as hi/lo planes
    {
      const int b = tid >> 6, d = tid & 63;
      const float v = x[((size_t)(b0 + b) * TT_ + t) * DD + d];
      ushort hi, lo; hl_split(v, hi, lo);
      sXh[b * SXB + d] = hi;
      sXl[b * SXB + d] = lo;
    }
    if (t == 0) {
      const int cc = tid & 255;
#pragma unroll
      for (int q = 0; q < 4; ++q) {
        const int b = (tid >> 8) * 4 + q;
        sAin[b * SA + cc] = 0.f;
        sAinh[b * SB + cc] = 0;
        sAinl[b * SB + cc] = 0;
      }
    }
    LBAR();

    if (t > 0) {
      const float dtv = times[t] - times[t - 1];
      f32x4 kv, ks;
      // k1 (reads h planes)
      feval(sAhh, sAhl, kv);
      ks = kv;
      wAin(0.5f * dtv, kv);
      LBAR();
      // k2
      feval(sAinh, sAinl, kv);
      ks += 2.0f * kv;
      wAin(0.5f * dtv, kv);
      LBAR();
      // k3
      feval(sAinh, sAinl, kv);
      ks += 2.0f * kv;
      wAin(dtv, kv);
      LBAR();
      // k4
      feval(sAinh, sAinl, kv);
      ks += kv;
      wAin(dtv * (1.0f / 6.0f), ks);  // sAin <- h_ode
      LBAR();
    }

    // ---- GRU: this wave computes r,z,hn,in for its 16 cols, all 16 batches ----
    {
      f32x4 ar = mm_rzt(sAinh, sAinl, sXh, sXl, wv, lane, Z);
      f32x4 az = mm_rzt(sAinh, sAinl, sXh, sXl, 16 + wv, lane, Z);
      f32x4 ahn = mm1(sAinh, sAinl, g_Whnp, wv, lane, Z);
      f32x4 ain = mm_in(sXh, sXl, wv, lane, Z);

#pragma unroll
      for (int q = 0; q < 4; ++q) {
        const int b = lq * 4 + q;
        const float gr = ar[q] + brz_r;
        const float gz = az[q] + brz_z;
        const float hn = ahn[q] + bn_h;
        const float gn = ain[q] + bn_i;
        const float hode = sAin[b * SA + c];
        const float rg = 1.f / (1.f + __expf(-gr));
        const float zg = 1.f / (1.f + __expf(-gz));
        const float ng = 1.f - 2.f / (__expf(2.f * (gn + rg * hn)) + 1.f);
        const float hnext = (1.f - zg) * ng + zg * hode;
        const float m = sM[b * TT_ + t];
        const float hnew = m * hnext + (1.f - m) * hode;
        // NT store: out is never re-read; don't let the stream allocate in L2
        __builtin_nontemporal_store(hnew, &out[((size_t)(b0 + b) * TT_ + t) * HH + c]);
        sAh[b * SA + c] = hnew;
        ushort hi, lo; hl_split(hnew, hi, lo);
        sAhh[b * SB + c] = hi;
        sAhl[b * SB + c] = lo;
      }
    }
    LBAR();
  }
}

extern "C" void kernel_launch(void* const* d_in, const int* in_sizes, int n_in,
                              void* d_out, int out_size, void* d_ws, size_t ws_size,
                              hipStream_t stream) {
  (void)in_sizes; (void)n_in; (void)d_ws; (void)ws_size; (void)out_size;
  const float* x     = (const float*)d_in[0];
  const float* times = (const float*)d_in[1];
  const float* mask  = (const float*)d_in[2];
  const float* W1    = (const float*)d_in[3];
  const float* b1    = (const float*)d_in[4];
  const float* W2    = (const float*)d_in[5];
  const float* b2    = (const float*)d_in[6];
  const float* Wih   = (const float*)d_in[7];
  const float* bih   = (const float*)d_in[8];
  const float* Whh   = (const float*)d_in[9];
  const float* bhh   = (const float*)d_in[10];
  float* out = (float*)d_out;

  hipLaunchKernelGGL(prep, dim3((376832 + 255) / 256), dim3(256), 0, stream,
                     W1, W2, Wih, Whh);
  hipLaunchKernelGGL(odegru_kernel, dim3(NBLK), dim3(NTHR), 0, stream,
                     x, times, mask, b1, b2, bih, bhh, out);
}

// Round 9
// 8413.102 us; speedup vs baseline: 1.0096x; 1.0096x over previous
//
#include <hip/hip_runtime.h>
#include <math.h>

#define TT_ 128
#define DD 64
#define HH 256
#define BB 16      // batch rows per block (MFMA M-tile)
#define NBLK 64    // 1024/16
#define NTHR 1024  // 16 waves, 1 N-tile (16 cols) per wave

// f32 LDS stride (elements): 260*4B = 1040B (odd multiple of 16B)
#define SA 260
// bf16 plane strides (elements): 264*2B = 528B, 72*2B = 144B (odd multiples of 16B)
#define SB 264
#define SXB 72

typedef short bf16x8 __attribute__((ext_vector_type(8)));
typedef float f32x4 __attribute__((ext_vector_type(4)));
typedef unsigned int uint;
typedef unsigned short ushort;

// ---- fragment-linear packed weights (bf16 hi/lo pairs), written by prep ----
// frag elem (tile t, oct o): W[t*16 + l%16][o*32 + (l/16)*8 + j], hi at +0, lo at +512
__device__ ushort g_W1p[16 * 8 * 2 * 512];    // W1  (256x256): t*8192 + o*1024
__device__ ushort g_W2p[16 * 8 * 2 * 512];    // W2  (256x256)
__device__ ushort g_Wrzp[32 * 10 * 2 * 512];  // Whh rows 0..511 (o<8) | Wih rows 0..511 (o=8,9): t*10240 + o*1024
__device__ ushort g_Whnp[16 * 8 * 2 * 512];   // Whh rows 512..767
__device__ ushort g_Winp[16 * 2 * 512];       // Wih rows 512..767 (hi only): t*1024 + o*512

__device__ __forceinline__ ushort bf16_rne(float f) {
  uint u = __builtin_bit_cast(uint, f);
  return (ushort)((u + 0x7fffu + ((u >> 16) & 1u)) >> 16);
}
__device__ __forceinline__ float bf16_f32(ushort h) {
  uint u = ((uint)h) << 16;
  return __builtin_bit_cast(float, u);
}
// truncation split: hi+lo reproduces f to ~2^-17 rel
__device__ __forceinline__ void hl_split(float f, ushort& hi, ushort& lo) {
  const uint u = __builtin_bit_cast(uint, f);
  hi = (ushort)(u >> 16);
  const float fh = __builtin_bit_cast(float, u & 0xffff0000u);
  lo = (ushort)(__builtin_bit_cast(uint, f - fh) >> 16);
}

__global__ __launch_bounds__(256) void prep(
    const float* __restrict__ W1, const float* __restrict__ W2,
    const float* __restrict__ Wih, const float* __restrict__ Whh)
{
  const int s = blockIdx.x * 256 + threadIdx.x;
  const int S1 = 16 * 8 * 512;
  const int S2 = S1 + 16 * 8 * 512;
  const int S3 = S2 + 32 * 10 * 512;
  const int S4 = S3 + 16 * 8 * 512;
  const int S5 = S4 + 16 * 2 * 512;
  if (s >= S5) return;

  if (s < S2) {  // W1 / W2
    const int r = (s < S1) ? s : s - S1;
    const int t = r / (8 * 512);
    const int o = (r / 512) & 7;
    const int pos = r & 511;
    const int l = pos >> 3, j = pos & 7;
    const int n = t * 16 + (l & 15);
    const int k = o * 32 + (l >> 4) * 8 + j;
    const float w = (s < S1) ? W1[n * HH + k] : W2[n * HH + k];
    ushort hi = bf16_rne(w);
    ushort lo = bf16_rne(w - bf16_f32(hi));
    ushort* dst = (s < S1) ? g_W1p : g_W2p;
    dst[((t * 8 + o) * 2) * 512 + pos] = hi;
    dst[((t * 8 + o) * 2 + 1) * 512 + pos] = lo;
  } else if (s < S3) {  // Wrz
    const int r = s - S2;
    const int t = r / (10 * 512);
    const int o = (r / 512) % 10;
    const int pos = r & 511;
    const int l = pos >> 3, j = pos & 7;
    const int n = t * 16 + (l & 15);
    float w;
    if (o < 8) w = Whh[n * HH + o * 32 + (l >> 4) * 8 + j];
    else       w = Wih[n * DD + (o - 8) * 32 + (l >> 4) * 8 + j];
    ushort hi = bf16_rne(w);
    ushort lo = bf16_rne(w - bf16_f32(hi));
    g_Wrzp[((t * 10 + o) * 2) * 512 + pos] = hi;
    g_Wrzp[((t * 10 + o) * 2 + 1) * 512 + pos] = lo;
  } else if (s < S4) {  // Whn
    const int r = s - S3;
    const int t = r / (8 * 512);
    const int o = (r / 512) & 7;
    const int pos = r & 511;
    const int l = pos >> 3, j = pos & 7;
    const int n = 512 + t * 16 + (l & 15);
    const float w = Whh[n * HH + o * 32 + (l >> 4) * 8 + j];
    ushort hi = bf16_rne(w);
    ushort lo = bf16_rne(w - bf16_f32(hi));
    g_Whnp[((t * 8 + o) * 2) * 512 + pos] = hi;
    g_Whnp[((t * 8 + o) * 2 + 1) * 512 + pos] = lo;
  } else {  // Win (hi only)
    const int r = s - S4;
    const int t = r / (2 * 512);
    const int o = (r / 512) & 1;
    const int pos = r & 511;
    const int l = pos >> 3, j = pos & 7;
    const int n = 512 + t * 16 + (l & 15);
    const float w = Wih[n * DD + o * 32 + (l >> 4) * 8 + j];
    g_Winp[(t * 2 + o) * 512 + pos] = bf16_rne(w);
  }
}

#define MFMA(A, B, C) __builtin_amdgcn_mfma_f32_16x16x32_bf16((A), (B), (C), 0, 0, 0)

// LDS-only barrier: waits lgkm only; the "memory" clobber also PINS global
// loads issued before it (they can't sink past), so pre-barrier weight loads
// stay in flight across the barrier and their latency overlaps the wait.
#define LBAR() asm volatile("s_waitcnt lgkmcnt(0)\ns_barrier" ::: "memory")

// Register-liveness fence for bursts not adjacent to a barrier.
__device__ __forceinline__ void sink16(const bf16x8* W, const bf16x8* L) {
  const f32x4 w0 = __builtin_bit_cast(f32x4, W[0]), w1 = __builtin_bit_cast(f32x4, W[1]);
  const f32x4 w2 = __builtin_bit_cast(f32x4, W[2]), w3 = __builtin_bit_cast(f32x4, W[3]);
  const f32x4 w4 = __builtin_bit_cast(f32x4, W[4]), w5 = __builtin_bit_cast(f32x4, W[5]);
  const f32x4 w6 = __builtin_bit_cast(f32x4, W[6]), w7 = __builtin_bit_cast(f32x4, W[7]);
  const f32x4 l0 = __builtin_bit_cast(f32x4, L[0]), l1 = __builtin_bit_cast(f32x4, L[1]);
  const f32x4 l2 = __builtin_bit_cast(f32x4, L[2]), l3 = __builtin_bit_cast(f32x4, L[3]);
  const f32x4 l4 = __builtin_bit_cast(f32x4, L[4]), l5 = __builtin_bit_cast(f32x4, L[5]);
  const f32x4 l6 = __builtin_bit_cast(f32x4, L[6]), l7 = __builtin_bit_cast(f32x4, L[7]);
  asm volatile("" :: "v"(w0), "v"(w1), "v"(w2), "v"(w3),
                     "v"(w4), "v"(w5), "v"(w6), "v"(w7),
                     "v"(l0), "v"(l1), "v"(l2), "v"(l3),
                     "v"(l4), "v"(l5), "v"(l6), "v"(l7));
}
__device__ __forceinline__ void sink2(const bf16x8 a, const bf16x8 b) {
  const f32x4 t0 = __builtin_bit_cast(f32x4, a);
  const f32x4 t1 = __builtin_bit_cast(f32x4, b);
  asm volatile("" :: "v"(t0), "v"(t1));
}

// Plain 16-load burst (no sink): used right before an LBAR, which pins it.
__device__ __forceinline__ void loadW(const ushort* __restrict__ base,
                                      bf16x8* wh, bf16x8* wl)
{
#pragma unroll
  for (int o = 0; o < 8; ++o) {
    wh[o] = *(const bf16x8*)(base + o * 1024);
    wl[o] = *(const bf16x8*)(base + o * 1024 + 512);
  }
}

// K=256, 3-term split accumulation on preloaded weight frags.
__device__ __forceinline__ f32x4 mmA16(const ushort* __restrict__ Ahi,
                                       const ushort* __restrict__ Alo,
                                       int aoff, const bf16x8* wh,
                                       const bf16x8* wl, f32x4 acc)
{
  f32x4 a0 = acc;
  f32x4 a1 = {0.f, 0.f, 0.f, 0.f};
#pragma unroll
  for (int o = 0; o < 8; ++o) {
    const bf16x8 ah = *(const bf16x8*)(Ahi + aoff + o * 32);
    const bf16x8 al = *(const bf16x8*)(Alo + aoff + o * 32);
    f32x4& ac = (o & 1) ? a1 : a0;
    ac = MFMA(ah, wh[o], ac);
    ac = MFMA(al, wh[o], ac);
    ac = MFMA(ah, wl[o], ac);
  }
  return a0 + a1;
}

// Self-loading (sink-burst) variants for GRU z/hn/in (no adjacent barrier).
__device__ __forceinline__ f32x4 mm1(const ushort* __restrict__ Ahi,
                                     const ushort* __restrict__ Alo,
                                     const ushort* __restrict__ pack,
                                     int tile, int lane, int aoff, f32x4 acc)
{
  const ushort* wp = pack + (size_t)tile * 8192 + lane * 8;
  bf16x8 wh[8], wl[8];
  loadW(wp, wh, wl);
  sink16(wh, wl);
  return mmA16(Ahi, Alo, aoff, wh, wl, acc);
}

__device__ __forceinline__ f32x4 mm_rzt(const ushort* __restrict__ Ahi,
                                        const ushort* __restrict__ Alo,
                                        const ushort* __restrict__ Xhi,
                                        const ushort* __restrict__ Xlo,
                                        int tile, int lane, int aoff, int xoff,
                                        f32x4 acc)
{
  const ushort* p = g_Wrzp + (size_t)tile * 10240 + lane * 8;
  bf16x8 wh[8], wl[8], wx[2];
  loadW(p, wh, wl);
  wx[0] = *(const bf16x8*)(p + 8 * 1024);
  wx[1] = *(const bf16x8*)(p + 9 * 1024);
  sink16(wh, wl);
  sink2(wx[0], wx[1]);
  f32x4 a = mmA16(Ahi, Alo, aoff, wh, wl, acc);
#pragma unroll
  for (int o = 0; o < 2; ++o) {
    const bf16x8 xh = *(const bf16x8*)(Xhi + xoff + o * 32);
    const bf16x8 xl = *(const bf16x8*)(Xlo + xoff + o * 32);
    a = MFMA(xh, wx[o], a);
    a = MFMA(xl, wx[o], a);
  }
  return a;
}

__device__ __forceinline__ f32x4 mm_in(const ushort* __restrict__ Xhi,
                                       const ushort* __restrict__ Xlo,
                                       int wv, int lane, int xoff, f32x4 acc)
{
  const ushort* pw = g_Winp + (size_t)wv * 1024 + lane * 8;
  bf16x8 w0 = *(const bf16x8*)(pw);
  bf16x8 w1 = *(const bf16x8*)(pw + 512);
  sink2(w0, w1);
  {
    const bf16x8 xh = *(const bf16x8*)(Xhi + xoff);
    const bf16x8 xl = *(const bf16x8*)(Xlo + xoff);
    acc = MFMA(xh, w0, acc);
    acc = MFMA(xl, w0, acc);
  }
  {
    const bf16x8 xh = *(const bf16x8*)(Xhi + xoff + 32);
    const bf16x8 xl = *(const bf16x8*)(Xlo + xoff + 32);
    acc = MFMA(xh, w1, acc);
    acc = MFMA(xl, w1, acc);
  }
  return acc;
}

__global__ __launch_bounds__(NTHR)
__attribute__((amdgpu_waves_per_eu(4, 4)))   // pin RA budget to 128 VGPR (4 waves/EU)
void odegru_kernel(
    const float* __restrict__ x, const float* __restrict__ times,
    const float* __restrict__ mask,
    const float* __restrict__ b1, const float* __restrict__ b2,
    const float* __restrict__ bih, const float* __restrict__ bhh,
    float* __restrict__ out)
{
  // f32 state
  __shared__ __align__(16) float sAh[BB * SA];    // h (full f32 state)
  __shared__ __align__(16) float sAin[BB * SA];   // h_ode / RK stage input (f32)
  // bf16 hi/lo matmul planes
  __shared__ __align__(16) ushort sAhh[BB * SB], sAhl[BB * SB];
  __shared__ __align__(16) ushort sAinh[BB * SB], sAinl[BB * SB];
  __shared__ __align__(16) ushort sUh[BB * SB], sUl[BB * SB];
  __shared__ __align__(16) ushort sXh[BB * SXB], sXl[BB * SXB];
  __shared__ __align__(16) float sM[BB * TT_];    // mask rows for this block

  const int tid = threadIdx.x;
  const int lane = tid & 63;
  const int wv = tid >> 6;     // wave 0..15, owns output col-tile wv
  const int l15 = lane & 15;
  const int lq = lane >> 4;    // 0..3
  const int b0 = blockIdx.x * BB;
  const int aoff = l15 * SB + lq * 8;
  const int xoff = l15 * SXB + lq * 8;

  const int c = wv * 16 + l15;       // this thread's output column
  const float b1c = b1[c];
  const float b2c = b2[c];
  const float brz_r = bih[c] + bhh[c];
  const float brz_z = bih[c + 256] + bhh[c + 256];
  const float bn_i = bih[c + 512];
  const float bn_h = bhh[c + 512];

  const f32x4 Z = {0.f, 0.f, 0.f, 0.f};

  const ushort* W1b = g_W1p + (size_t)wv * 8192 + lane * 8;
  const ushort* W2b = g_W2p + (size_t)wv * 8192 + lane * 8;
  const ushort* Wrzr = g_Wrzp + (size_t)wv * 10240 + lane * 8;

  // stage mask rows once
  sM[tid] = mask[(size_t)b0 * TT_ + tid];
  sM[tid + 1024] = mask[(size_t)b0 * TT_ + tid + 1024];

  bf16x8 p0h[8], p0l[8], p1h[8], p1l[8], px[2];

  auto storeU = [&](const f32x4& a) {
#pragma unroll
    for (int q = 0; q < 4; ++q) {
      const int b = lq * 4 + q;
      const float u = fmaxf(a[q] + b1c, 0.f);
      ushort hi, lo; hl_split(u, hi, lo);
      sUh[b * SB + c] = hi;
      sUl[b * SB + c] = lo;
    }
  };
  auto wAin = [&](float coef, const f32x4& v) {
#pragma unroll
    for (int q = 0; q < 4; ++q) {
      const int b = lq * 4 + q;
      const float nv = sAh[b * SA + c] + coef * v[q];
      sAin[b * SA + c] = nv;
      ushort hi, lo; hl_split(nv, hi, lo);
      sAinh[b * SB + c] = hi;
      sAinl[b * SB + c] = lo;
    }
  };
  auto loadRZr = [&]() {
    loadW(Wrzr, p0h, p0l);
    px[0] = *(const bf16x8*)(Wrzr + 8 * 1024);
    px[1] = *(const bf16x8*)(Wrzr + 9 * 1024);
  };

  for (int t = 0; t < TT_; ++t) {
    // stage x[:, t, :] as hi/lo planes
    {
      const int b = tid >> 6, d = tid & 63;
      const float v = x[((size_t)(b0 + b) * TT_ + t) * DD + d];
      ushort hi, lo; hl_split(v, hi, lo);
      sXh[b * SXB + d] = hi;
      sXl[b * SXB + d] = lo;
    }
    if (t == 0) {
      const int cc = tid & 255;
#pragma unroll
      for (int q = 0; q < 4; ++q) {
        const int b = (tid >> 8) * 4 + q;
        sAin[b * SA + cc] = 0.f;
        sAinh[b * SB + cc] = 0;
        sAinl[b * SB + cc] = 0;
      }
      loadRZr();  // GRU r-weights fly across the next barrier
    }
    // else: p0 holds W1 (issued before previous step's closing LBAR)
    LBAR();

    if (t > 0) {
      const float dtv = times[t] - times[t - 1];
      f32x4 kv, ks, a;
      // ---- k1 (reads h planes; W1 already in p0) ----
      a = mmA16(sAhh, sAhl, aoff, p0h, p0l, Z);
      storeU(a);
      loadW(W2b, p1h, p1l);          // W2 flies across barrier
      LBAR();
      kv = mmA16(sUh, sUl, aoff, p1h, p1l, Z) + b2c;
      ks = kv;
      wAin(0.5f * dtv, kv);
      loadW(W1b, p0h, p0l);          // next stage W1 flies across barrier
      LBAR();
      // ---- k2 ----
      a = mmA16(sAinh, sAinl, aoff, p0h, p0l, Z);
      storeU(a);
      loadW(W2b, p1h, p1l);
      LBAR();
      kv = mmA16(sUh, sUl, aoff, p1h, p1l, Z) + b2c;
      ks += 2.0f * kv;
      wAin(0.5f * dtv, kv);
      loadW(W1b, p0h, p0l);
      LBAR();
      // ---- k3 ----
      a = mmA16(sAinh, sAinl, aoff, p0h, p0l, Z);
      storeU(a);
      loadW(W2b, p1h, p1l);
      LBAR();
      kv = mmA16(sUh, sUl, aoff, p1h, p1l, Z) + b2c;
      ks += 2.0f * kv;
      wAin(dtv, kv);
      loadW(W1b, p0h, p0l);
      LBAR();
      // ---- k4 ----
      a = mmA16(sAinh, sAinl, aoff, p0h, p0l, Z);
      storeU(a);
      loadW(W2b, p1h, p1l);
      LBAR();
      kv = mmA16(sUh, sUl, aoff, p1h, p1l, Z) + b2c;
      ks += kv;
      wAin(dtv * (1.0f / 6.0f), ks);  // sAin <- h_ode
      loadRZr();                      // GRU r-weights fly across barrier
      LBAR();
    }

    // ---- GRU: r from preloaded frags; z/hn/in self-loading bursts ----
    {
      f32x4 ar = mmA16(sAinh, sAinl, aoff, p0h, p0l, Z);
#pragma unroll
      for (int o = 0; o < 2; ++o) {
        const bf16x8 xh = *(const bf16x8*)(sXh + xoff + o * 32);
        const bf16x8 xl = *(const bf16x8*)(sXl + xoff + o * 32);
        ar = MFMA(xh, px[o], ar);
        ar = MFMA(xl, px[o], ar);
      }
      f32x4 az = mm_rzt(sAinh, sAinl, sXh, sXl, 16 + wv, lane, aoff, xoff, Z);
      f32x4 ahn = mm1(sAinh, sAinl, g_Whnp, wv, lane, aoff, Z);
      f32x4 ain = mm_in(sXh, sXl, wv, lane, xoff, Z);

#pragma unroll
      for (int q = 0; q < 4; ++q) {
        const int b = lq * 4 + q;
        const float gr = ar[q] + brz_r;
        const float gz = az[q] + brz_z;
        const float hn = ahn[q] + bn_h;
        const float gn = ain[q] + bn_i;
        const float hode = sAin[b * SA + c];
        const float rg = 1.f / (1.f + __expf(-gr));
        const float zg = 1.f / (1.f + __expf(-gz));
        const float ng = 1.f - 2.f / (__expf(2.f * (gn + rg * hn)) + 1.f);
        const float hnext = (1.f - zg) * ng + zg * hode;
        const float m = sM[b * TT_ + t];
        const float hnew = m * hnext + (1.f - m) * hode;
        __builtin_nontemporal_store(hnew, &out[((size_t)(b0 + b) * TT_ + t) * HH + c]);
        sAh[b * SA + c] = hnew;
        ushort hi, lo; hl_split(hnew, hi, lo);
        sAhh[b * SB + c] = hi;
        sAhl[b * SB + c] = lo;
      }
    }
    loadW(W1b, p0h, p0l);   // next step's k1 W1 flies across closing barrier
    LBAR();
  }
}

extern "C" void kernel_launch(void* const* d_in, const int* in_sizes, int n_in,
                              void* d_out, int out_size, void* d_ws, size_t ws_size,
                              hipStream_t stream) {
  (void)in_sizes; (void)n_in; (void)d_ws; (void)ws_size; (void)out_size;
  const float* x     = (const float*)d_in[0];
  const float* times = (const float*)d_in[1];
  const float* mask  = (const float*)d_in[2];
  const float* W1    = (const float*)d_in[3];
  const float* b1    = (const float*)d_in[4];
  const float* W2    = (const float*)d_in[5];
  const float* b2    = (const float*)d_in[6];
  const float* Wih   = (const float*)d_in[7];
  const float* bih   = (const float*)d_in[8];
  const float* Whh   = (const float*)d_in[9];
  const float* bhh   = (const float*)d_in[10];
  float* out = (float*)d_out;

  hipLaunchKernelGGL(prep, dim3((376832 + 255) / 256), dim3(256), 0, stream,
                     W1, W2, Wih, Whh);
  hipLaunchKernelGGL(odegru_kernel, dim3(NBLK), dim3(NTHR), 0, stream,
                     x, times, mask, b1, b2, bih, bhh, out);
}

// Round 10
// 8372.124 us; speedup vs baseline: 1.0145x; 1.0049x over previous
//
#include <hip/hip_runtime.h>
#include <math.h>

#define TT_ 128
#define DD 64
#define HH 256
#define BB 16      // batch rows per block (MFMA M-tile)
#define NBLK 64    // 1024/16
#define NTHR 512   // 8 waves; empirically gets 128-VGPR budget (R2/R3)

// f32 LDS stride (elements): 260*4B = 1040B (odd multiple of 16B)
#define SA 260
// bf16 plane strides (elements): 264*2B = 528B, 72*2B = 144B (odd multiples of 16B)
#define SB 264
#define SXB 72

typedef short bf16x8 __attribute__((ext_vector_type(8)));
typedef float f32x4 __attribute__((ext_vector_type(4)));
typedef unsigned int uint;
typedef unsigned short ushort;

// ---- fragment-linear packed weights (bf16 hi/lo pairs), written by prep ----
// frag elem (tile t, oct o): W[t*16 + l%16][o*32 + (l/16)*8 + j], hi at +0, lo at +512
__device__ ushort g_W1p[16 * 8 * 2 * 512];    // W1  (256x256): t*8192 + o*1024
__device__ ushort g_W2p[16 * 8 * 2 * 512];    // W2  (256x256)
__device__ ushort g_Wrzp[32 * 10 * 2 * 512];  // Whh rows 0..511 (o<8) | Wih rows 0..511 (o=8,9): t*10240 + o*1024
__device__ ushort g_Whnp[16 * 8 * 2 * 512];   // Whh rows 512..767
__device__ ushort g_Winp[16 * 2 * 512];       // Wih rows 512..767 (hi only): t*1024 + o*512

__device__ __forceinline__ ushort bf16_rne(float f) {
  uint u = __builtin_bit_cast(uint, f);
  return (ushort)((u + 0x7fffu + ((u >> 16) & 1u)) >> 16);
}
__device__ __forceinline__ float bf16_f32(ushort h) {
  uint u = ((uint)h) << 16;
  return __builtin_bit_cast(float, u);
}
// truncation split: hi+lo reproduces f to ~2^-17 rel
__device__ __forceinline__ void hl_split(float f, ushort& hi, ushort& lo) {
  const uint u = __builtin_bit_cast(uint, f);
  hi = (ushort)(u >> 16);
  const float fh = __builtin_bit_cast(float, u & 0xffff0000u);
  lo = (ushort)(__builtin_bit_cast(uint, f - fh) >> 16);
}

__global__ __launch_bounds__(256) void prep(
    const float* __restrict__ W1, const float* __restrict__ W2,
    const float* __restrict__ Wih, const float* __restrict__ Whh)
{
  const int s = blockIdx.x * 256 + threadIdx.x;
  const int S1 = 16 * 8 * 512;
  const int S2 = S1 + 16 * 8 * 512;
  const int S3 = S2 + 32 * 10 * 512;
  const int S4 = S3 + 16 * 8 * 512;
  const int S5 = S4 + 16 * 2 * 512;
  if (s >= S5) return;

  if (s < S2) {  // W1 / W2
    const int r = (s < S1) ? s : s - S1;
    const int t = r / (8 * 512);
    const int o = (r / 512) & 7;
    const int pos = r & 511;
    const int l = pos >> 3, j = pos & 7;
    const int n = t * 16 + (l & 15);
    const int k = o * 32 + (l >> 4) * 8 + j;
    const float w = (s < S1) ? W1[n * HH + k] : W2[n * HH + k];
    ushort hi = bf16_rne(w);
    ushort lo = bf16_rne(w - bf16_f32(hi));
    ushort* dst = (s < S1) ? g_W1p : g_W2p;
    dst[((t * 8 + o) * 2) * 512 + pos] = hi;
    dst[((t * 8 + o) * 2 + 1) * 512 + pos] = lo;
  } else if (s < S3) {  // Wrz
    const int r = s - S2;
    const int t = r / (10 * 512);
    const int o = (r / 512) % 10;
    const int pos = r & 511;
    const int l = pos >> 3, j = pos & 7;
    const int n = t * 16 + (l & 15);
    float w;
    if (o < 8) w = Whh[n * HH + o * 32 + (l >> 4) * 8 + j];
    else       w = Wih[n * DD + (o - 8) * 32 + (l >> 4) * 8 + j];
    ushort hi = bf16_rne(w);
    ushort lo = bf16_rne(w - bf16_f32(hi));
    g_Wrzp[((t * 10 + o) * 2) * 512 + pos] = hi;
    g_Wrzp[((t * 10 + o) * 2 + 1) * 512 + pos] = lo;
  } else if (s < S4) {  // Whn
    const int r = s - S3;
    const int t = r / (8 * 512);
    const int o = (r / 512) & 7;
    const int pos = r & 511;
    const int l = pos >> 3, j = pos & 7;
    const int n = 512 + t * 16 + (l & 15);
    const float w = Whh[n * HH + o * 32 + (l >> 4) * 8 + j];
    ushort hi = bf16_rne(w);
    ushort lo = bf16_rne(w - bf16_f32(hi));
    g_Whnp[((t * 8 + o) * 2) * 512 + pos] = hi;
    g_Whnp[((t * 8 + o) * 2 + 1) * 512 + pos] = lo;
  } else {  // Win (hi only)
    const int r = s - S4;
    const int t = r / (2 * 512);
    const int o = (r / 512) & 1;
    const int pos = r & 511;
    const int l = pos >> 3, j = pos & 7;
    const int n = 512 + t * 16 + (l & 15);
    const float w = Wih[n * DD + o * 32 + (l >> 4) * 8 + j];
    g_Winp[(t * 2 + o) * 512 + pos] = bf16_rne(w);
  }
}

#define MFMA(A, B, C) __builtin_amdgcn_mfma_f32_16x16x32_bf16((A), (B), (C), 0, 0, 0)

// LDS-only barrier: waits lgkm only (keeps global loads in flight across it)
#define LBAR() asm volatile("s_waitcnt lgkmcnt(0)\ns_barrier" ::: "memory")

// Register-liveness fence: forces the 16-frag weight burst simultaneously live
// so the allocator can't re-roll it into serial load->use chains.
__device__ __forceinline__ void sink16(const bf16x8* W, const bf16x8* L) {
  const f32x4 w0 = __builtin_bit_cast(f32x4, W[0]), w1 = __builtin_bit_cast(f32x4, W[1]);
  const f32x4 w2 = __builtin_bit_cast(f32x4, W[2]), w3 = __builtin_bit_cast(f32x4, W[3]);
  const f32x4 w4 = __builtin_bit_cast(f32x4, W[4]), w5 = __builtin_bit_cast(f32x4, W[5]);
  const f32x4 w6 = __builtin_bit_cast(f32x4, W[6]), w7 = __builtin_bit_cast(f32x4, W[7]);
  const f32x4 l0 = __builtin_bit_cast(f32x4, L[0]), l1 = __builtin_bit_cast(f32x4, L[1]);
  const f32x4 l2 = __builtin_bit_cast(f32x4, L[2]), l3 = __builtin_bit_cast(f32x4, L[3]);
  const f32x4 l4 = __builtin_bit_cast(f32x4, L[4]), l5 = __builtin_bit_cast(f32x4, L[5]);
  const f32x4 l6 = __builtin_bit_cast(f32x4, L[6]), l7 = __builtin_bit_cast(f32x4, L[7]);
  asm volatile("" :: "v"(w0), "v"(w1), "v"(w2), "v"(w3),
                     "v"(w4), "v"(w5), "v"(w6), "v"(w7),
                     "v"(l0), "v"(l1), "v"(l2), "v"(l3),
                     "v"(l4), "v"(l5), "v"(l6), "v"(l7));
}
__device__ __forceinline__ void sink2(const bf16x8 a, const bf16x8 b) {
  const f32x4 t0 = __builtin_bit_cast(f32x4, a);
  const f32x4 t1 = __builtin_bit_cast(f32x4, b);
  asm volatile("" :: "v"(t0), "v"(t1));
}

__device__ __forceinline__ void loadW(const ushort* __restrict__ base,
                                      bf16x8* wh, bf16x8* wl)
{
#pragma unroll
  for (int o = 0; o < 8; ++o) {
    wh[o] = *(const bf16x8*)(base + o * 1024);
    wl[o] = *(const bf16x8*)(base + o * 1024 + 512);
  }
}

// K=256, 3-term split accumulation on preloaded weight frags (2 acc chains).
__device__ __forceinline__ f32x4 mmA16(const ushort* __restrict__ Ahi,
                                       const ushort* __restrict__ Alo,
                                       int aoff, const bf16x8* wh,
                                       const bf16x8* wl, f32x4 acc)
{
  f32x4 a0 = acc;
  f32x4 a1 = {0.f, 0.f, 0.f, 0.f};
#pragma unroll
  for (int o = 0; o < 8; ++o) {
    const bf16x8 ah = *(const bf16x8*)(Ahi + aoff + o * 32);
    const bf16x8 al = *(const bf16x8*)(Alo + aoff + o * 32);
    f32x4& ac = (o & 1) ? a1 : a0;
    ac = MFMA(ah, wh[o], ac);
    ac = MFMA(al, wh[o], ac);
    ac = MFMA(ah, wl[o], ac);
  }
  return a0 + a1;
}

// Self-loading burst matmul, one N-tile of `pack` (8192-stride packs)
__device__ __forceinline__ f32x4 mm1(const ushort* __restrict__ Ahi,
                                     const ushort* __restrict__ Alo,
                                     const ushort* __restrict__ pack,
                                     int tile, int lane, int aoff, f32x4 acc)
{
  const ushort* wp = pack + (size_t)tile * 8192 + lane * 8;
  bf16x8 wh[8], wl[8];
  loadW(wp, wh, wl);
  sink16(wh, wl);
  return mmA16(Ahi, Alo, aoff, wh, wl, acc);
}

// One Wrzp tile: K=256 h-part (3-term) + K=64 x-part (2-term)
__device__ __forceinline__ f32x4 mm_rzt(const ushort* __restrict__ Ahi,
                                        const ushort* __restrict__ Alo,
                                        const ushort* __restrict__ Xhi,
                                        const ushort* __restrict__ Xlo,
                                        int tile, int lane, int aoff, int xoff,
                                        f32x4 acc)
{
  const ushort* p = g_Wrzp + (size_t)tile * 10240 + lane * 8;
  bf16x8 wh[8], wl[8], wx[2];
  loadW(p, wh, wl);
  wx[0] = *(const bf16x8*)(p + 8 * 1024);
  wx[1] = *(const bf16x8*)(p + 9 * 1024);
  sink16(wh, wl);
  sink2(wx[0], wx[1]);
  f32x4 a = mmA16(Ahi, Alo, aoff, wh, wl, acc);
#pragma unroll
  for (int o = 0; o < 2; ++o) {
    const bf16x8 xh = *(const bf16x8*)(Xhi + xoff + o * 32);
    const bf16x8 xl = *(const bf16x8*)(Xlo + xoff + o * 32);
    a = MFMA(xh, wx[o], a);
    a = MFMA(xl, wx[o], a);
  }
  return a;
}

// n-gate x-side: K=64, hi-only weights, 2-term
__device__ __forceinline__ f32x4 mm_in(const ushort* __restrict__ Xhi,
                                       const ushort* __restrict__ Xlo,
                                       int tile, int lane, int xoff, f32x4 acc)
{
  const ushort* pw = g_Winp + (size_t)tile * 1024 + lane * 8;
  bf16x8 w0 = *(const bf16x8*)(pw);
  bf16x8 w1 = *(const bf16x8*)(pw + 512);
  sink2(w0, w1);
  {
    const bf16x8 xh = *(const bf16x8*)(Xhi + xoff);
    const bf16x8 xl = *(const bf16x8*)(Xlo + xoff);
    acc = MFMA(xh, w0, acc);
    acc = MFMA(xl, w0, acc);
  }
  {
    const bf16x8 xh = *(const bf16x8*)(Xhi + xoff + 32);
    const bf16x8 xl = *(const bf16x8*)(Xlo + xoff + 32);
    acc = MFMA(xh, w1, acc);
    acc = MFMA(xl, w1, acc);
  }
  return acc;
}

__global__ __launch_bounds__(NTHR, 2) void odegru_kernel(
    const float* __restrict__ x, const float* __restrict__ times,
    const float* __restrict__ mask,
    const float* __restrict__ b1, const float* __restrict__ b2,
    const float* __restrict__ bih, const float* __restrict__ bhh,
    float* __restrict__ out)
{
  // f32 state
  __shared__ __align__(16) float sAh[BB * SA];    // h (full f32 state)
  __shared__ __align__(16) float sAin[BB * SA];   // h_ode / RK stage input (f32)
  // bf16 hi/lo matmul planes
  __shared__ __align__(16) ushort sAhh[BB * SB], sAhl[BB * SB];
  __shared__ __align__(16) ushort sAinh[BB * SB], sAinl[BB * SB];
  __shared__ __align__(16) ushort sUh[BB * SB], sUl[BB * SB];
  __shared__ __align__(16) ushort sXh[BB * SXB], sXl[BB * SXB];
  __shared__ __align__(16) float sM[BB * TT_];    // mask rows for this block

  const int tid = threadIdx.x;
  const int lane = tid & 63;
  const int w = tid >> 6;      // wave 0..7, owns tiles t0=2w, t0+1
  const int t0 = 2 * w;
  const int l15 = lane & 15;
  const int lq = lane >> 4;    // 0..3
  const int b0 = blockIdx.x * BB;
  const int aoff = l15 * SB + lq * 8;
  const int xoff = l15 * SXB + lq * 8;

  const int c0 = t0 * 16 + l15;      // this thread's two output columns
  const int c1 = c0 + 16;
  const float b1c0 = b1[c0], b1c1 = b1[c1];
  const float b2c0 = b2[c0], b2c1 = b2[c1];
  const float brz_r0 = bih[c0] + bhh[c0], brz_r1 = bih[c1] + bhh[c1];
  const float brz_z0 = bih[c0 + 256] + bhh[c0 + 256], brz_z1 = bih[c1 + 256] + bhh[c1 + 256];
  const float bn_i0 = bih[c0 + 512], bn_i1 = bih[c1 + 512];
  const float bn_h0 = bhh[c0 + 512], bn_h1 = bhh[c1 + 512];

  const f32x4 Z = {0.f, 0.f, 0.f, 0.f};

  // stage mask rows once (BB*TT_ = 2048 floats, 512 threads x 4)
  sM[tid] = mask[(size_t)b0 * TT_ + tid];
  sM[tid + 512] = mask[(size_t)b0 * TT_ + tid + 512];
  sM[tid + 1024] = mask[(size_t)b0 * TT_ + tid + 1024];
  sM[tid + 1536] = mask[(size_t)b0 * TT_ + tid + 1536];

  // feval: A-planes -> kv0,kv1 (per-thread: cols c0,c1, batches lq*4+q)
  auto feval = [&](const ushort* Ahi, const ushort* Alo, f32x4& kv0, f32x4& kv1) {
    f32x4 a0 = mm1(Ahi, Alo, g_W1p, t0, lane, aoff, Z);
    f32x4 a1 = mm1(Ahi, Alo, g_W1p, t0 + 1, lane, aoff, Z);
#pragma unroll
    for (int q = 0; q < 4; ++q) {
      const int b = lq * 4 + q;
      const float u0 = fmaxf(a0[q] + b1c0, 0.f);
      const float u1 = fmaxf(a1[q] + b1c1, 0.f);
      ushort hi, lo;
      hl_split(u0, hi, lo); sUh[b * SB + c0] = hi; sUl[b * SB + c0] = lo;
      hl_split(u1, hi, lo); sUh[b * SB + c1] = hi; sUl[b * SB + c1] = lo;
    }
    LBAR();
    f32x4 p0 = mm1(sUh, sUl, g_W2p, t0, lane, aoff, Z);
    f32x4 p1 = mm1(sUh, sUl, g_W2p, t0 + 1, lane, aoff, Z);
    kv0 = p0 + b2c0;
    kv1 = p1 + b2c1;
  };

  // sAin <- sAh + coef*v (f32) and refresh Ain planes (both cols)
  auto wAin = [&](float coef, const f32x4& v0, const f32x4& v1) {
#pragma unroll
    for (int q = 0; q < 4; ++q) {
      const int b = lq * 4 + q;
      const float nv0 = sAh[b * SA + c0] + coef * v0[q];
      const float nv1 = sAh[b * SA + c1] + coef * v1[q];
      sAin[b * SA + c0] = nv0;
      sAin[b * SA + c1] = nv1;
      ushort hi, lo;
      hl_split(nv0, hi, lo); sAinh[b * SB + c0] = hi; sAinl[b * SB + c0] = lo;
      hl_split(nv1, hi, lo); sAinh[b * SB + c1] = hi; sAinl[b * SB + c1] = lo;
    }
  };

  for (int t = 0; t < TT_; ++t) {
    // stage x[:, t, :] as hi/lo planes (512 thr: 2 values each)
    {
      const int b = tid >> 5, d = (tid & 31) * 2;
      const float2 v = *(const float2*)&x[((size_t)(b0 + b) * TT_ + t) * DD + d];
      ushort hi, lo;
      hl_split(v.x, hi, lo); sXh[b * SXB + d] = hi; sXl[b * SXB + d] = lo;
      hl_split(v.y, hi, lo); sXh[b * SXB + d + 1] = hi; sXl[b * SXB + d + 1] = lo;
    }
    if (t == 0) {
#pragma unroll
      for (int q = 0; q < 8; ++q) {
        const int idx = tid * 8 + q;
        const int b = idx >> 8, cc = idx & 255;
        sAin[b * SA + cc] = 0.f;
        sAinh[b * SB + cc] = 0;
        sAinl[b * SB + cc] = 0;
      }
    }
    LBAR();

    if (t > 0) {
      const float dtv = times[t] - times[t - 1];
      f32x4 kv0, kv1, ks0, ks1;
      // k1 (reads h planes)
      feval(sAhh, sAhl, kv0, kv1);
      ks0 = kv0; ks1 = kv1;
      wAin(0.5f * dtv, kv0, kv1);
      LBAR();
      // k2
      feval(sAinh, sAinl, kv0, kv1);
      ks0 += 2.0f * kv0; ks1 += 2.0f * kv1;
      wAin(0.5f * dtv, kv0, kv1);
      LBAR();
      // k3
      feval(sAinh, sAinl, kv0, kv1);
      ks0 += 2.0f * kv0; ks1 += 2.0f * kv1;
      wAin(dtv, kv0, kv1);
      LBAR();
      // k4
      feval(sAinh, sAinl, kv0, kv1);
      ks0 += kv0; ks1 += kv1;
      wAin(dtv * (1.0f / 6.0f), ks0, ks1);  // sAin <- h_ode
      LBAR();
    }

    // ---- GRU: this wave computes r,z,hn,in for its 32 cols, all 16 batches ----
    {
      f32x4 ar0 = mm_rzt(sAinh, sAinl, sXh, sXl, t0, lane, aoff, xoff, Z);
      f32x4 ar1 = mm_rzt(sAinh, sAinl, sXh, sXl, t0 + 1, lane, aoff, xoff, Z);
      f32x4 az0 = mm_rzt(sAinh, sAinl, sXh, sXl, 16 + t0, lane, aoff, xoff, Z);
      f32x4 az1 = mm_rzt(sAinh, sAinl, sXh, sXl, 16 + t0 + 1, lane, aoff, xoff, Z);
      f32x4 ahn0 = mm1(sAinh, sAinl, g_Whnp, t0, lane, aoff, Z);
      f32x4 ahn1 = mm1(sAinh, sAinl, g_Whnp, t0 + 1, lane, aoff, Z);
      f32x4 ain0 = mm_in(sXh, sXl, t0, lane, xoff, Z);
      f32x4 ain1 = mm_in(sXh, sXl, t0 + 1, lane, xoff, Z);

#pragma unroll
      for (int q = 0; q < 4; ++q) {
        const int b = lq * 4 + q;
        const float m = sM[b * TT_ + t];
        // col c0
        {
          const float gr = ar0[q] + brz_r0;
          const float gz = az0[q] + brz_z0;
          const float hn = ahn0[q] + bn_h0;
          const float gn = ain0[q] + bn_i0;
          const float hode = sAin[b * SA + c0];
          const float rg = 1.f / (1.f + __expf(-gr));
          const float zg = 1.f / (1.f + __expf(-gz));
          const float ng = 1.f - 2.f / (__expf(2.f * (gn + rg * hn)) + 1.f);
          const float hnext = (1.f - zg) * ng + zg * hode;
          const float hnew = m * hnext + (1.f - m) * hode;
          __builtin_nontemporal_store(hnew, &out[((size_t)(b0 + b) * TT_ + t) * HH + c0]);
          sAh[b * SA + c0] = hnew;
          ushort hi, lo; hl_split(hnew, hi, lo);
          sAhh[b * SB + c0] = hi;
          sAhl[b * SB + c0] = lo;
        }
        // col c1
        {
          const float gr = ar1[q] + brz_r1;
          const float gz = az1[q] + brz_z1;
          const float hn = ahn1[q] + bn_h1;
          const float gn = ain1[q] + bn_i1;
          const float hode = sAin[b * SA + c1];
          const float rg = 1.f / (1.f + __expf(-gr));
          const float zg = 1.f / (1.f + __expf(-gz));
          const float ng = 1.f - 2.f / (__expf(2.f * (gn + rg * hn)) + 1.f);
          const float hnext = (1.f - zg) * ng + zg * hode;
          const float hnew = m * hnext + (1.f - m) * hode;
          __builtin_nontemporal_store(hnew, &out[((size_t)(b0 + b) * TT_ + t) * HH + c1]);
          sAh[b * SA + c1] = hnew;
          ushort hi, lo; hl_split(hnew, hi, lo);
          sAhh[b * SB + c1] = hi;
          sAhl[b * SB + c1] = lo;
        }
      }
    }
    LBAR();
  }
}

extern "C" void kernel_launch(void* const* d_in, const int* in_sizes, int n_in,
                              void* d_out, int out_size, void* d_ws, size_t ws_size,
                              hipStream_t stream) {
  (void)in_sizes; (void)n_in; (void)d_ws; (void)ws_size; (void)out_size;
  const float* x     = (const float*)d_in[0];
  const float* times = (const float*)d_in[1];
  const float* mask  = (const float*)d_in[2];
  const float* W1    = (const float*)d_in[3];
  const float* b1    = (const float*)d_in[4];
  const float* W2    = (const float*)d_in[5];
  const float* b2    = (const float*)d_in[6];
  const float* Wih   = (const float*)d_in[7];
  const float* bih   = (const float*)d_in[8];
  const float* Whh   = (const float*)d_in[9];
  const float* bhh   = (const float*)d_in[10];
  float* out = (float*)d_out;

  hipLaunchKernelGGL(prep, dim3((376832 + 255) / 256), dim3(256), 0, stream,
                     W1, W2, Wih, Whh);
  hipLaunchKernelGGL(odegru_kernel, dim3(NBLK), dim3(NTHR), 0, stream,
                     x, times, mask, b1, b2, bih, bhh, out);
}

// Round 11
// 6967.325 us; speedup vs baseline: 1.2191x; 1.2016x over previous
//
#include <hip/hip_runtime.h>
#include <math.h>

#define TT_ 128
#define DD 64
#define HH 256
#define BB 16      // batch rows per block (MFMA M-tile)
#define NBLK 64    // 1024/16
#define NTHR 1024  // 16 waves, 1 N-tile (16 cols) per wave

// f32 LDS stride (elements): 260*4B = 1040B (odd multiple of 16B)
#define SA 260
// bf16 plane strides (elements): 264*2B = 528B, 72*2B = 144B (odd multiples of 16B)
#define SB 264
#define SXB 72

typedef short bf16x8 __attribute__((ext_vector_type(8)));
typedef float f32x4 __attribute__((ext_vector_type(4)));
typedef unsigned int uint;
typedef unsigned short ushort;

// ---- fragment-linear packed weights (bf16 hi/lo pairs), written by prep ----
// frag elem (tile t, oct o): W[t*16 + l%16][o*32 + (l/16)*8 + j], hi at +0, lo at +512
__device__ ushort g_W1p[16 * 8 * 2 * 512];    // W1  (256x256): t*8192 + o*1024
__device__ ushort g_W2p[16 * 8 * 2 * 512];    // W2  (256x256)
__device__ ushort g_Wrzp[32 * 10 * 2 * 512];  // Whh rows 0..511 (o<8) | Wih rows 0..511 (o=8,9): t*10240 + o*1024
__device__ ushort g_Whnp[16 * 8 * 2 * 512];   // Whh rows 512..767
__device__ ushort g_Winp[16 * 2 * 512];       // Wih rows 512..767 (hi only): t*1024 + o*512

__device__ __forceinline__ ushort bf16_rne(float f) {
  uint u = __builtin_bit_cast(uint, f);
  return (ushort)((u + 0x7fffu + ((u >> 16) & 1u)) >> 16);
}
__device__ __forceinline__ float bf16_f32(ushort h) {
  uint u = ((uint)h) << 16;
  return __builtin_bit_cast(float, u);
}
// truncation split: hi+lo reproduces f to ~2^-17 rel
__device__ __forceinline__ void hl_split(float f, ushort& hi, ushort& lo) {
  const uint u = __builtin_bit_cast(uint, f);
  hi = (ushort)(u >> 16);
  const float fh = __builtin_bit_cast(float, u & 0xffff0000u);
  lo = (ushort)(__builtin_bit_cast(uint, f - fh) >> 16);
}

__global__ __launch_bounds__(256) void prep(
    const float* __restrict__ W1, const float* __restrict__ W2,
    const float* __restrict__ Wih, const float* __restrict__ Whh)
{
  const int s = blockIdx.x * 256 + threadIdx.x;
  const int S1 = 16 * 8 * 512;
  const int S2 = S1 + 16 * 8 * 512;
  const int S3 = S2 + 32 * 10 * 512;
  const int S4 = S3 + 16 * 8 * 512;
  const int S5 = S4 + 16 * 2 * 512;
  if (s >= S5) return;

  if (s < S2) {  // W1 / W2
    const int r = (s < S1) ? s : s - S1;
    const int t = r / (8 * 512);
    const int o = (r / 512) & 7;
    const int pos = r & 511;
    const int l = pos >> 3, j = pos & 7;
    const int n = t * 16 + (l & 15);
    const int k = o * 32 + (l >> 4) * 8 + j;
    const float w = (s < S1) ? W1[n * HH + k] : W2[n * HH + k];
    ushort hi = bf16_rne(w);
    ushort lo = bf16_rne(w - bf16_f32(hi));
    ushort* dst = (s < S1) ? g_W1p : g_W2p;
    dst[((t * 8 + o) * 2) * 512 + pos] = hi;
    dst[((t * 8 + o) * 2 + 1) * 512 + pos] = lo;
  } else if (s < S3) {  // Wrz
    const int r = s - S2;
    const int t = r / (10 * 512);
    const int o = (r / 512) % 10;
    const int pos = r & 511;
    const int l = pos >> 3, j = pos & 7;
    const int n = t * 16 + (l & 15);
    float w;
    if (o < 8) w = Whh[n * HH + o * 32 + (l >> 4) * 8 + j];
    else       w = Wih[n * DD + (o - 8) * 32 + (l >> 4) * 8 + j];
    ushort hi = bf16_rne(w);
    ushort lo = bf16_rne(w - bf16_f32(hi));
    g_Wrzp[((t * 10 + o) * 2) * 512 + pos] = hi;
    g_Wrzp[((t * 10 + o) * 2 + 1) * 512 + pos] = lo;
  } else if (s < S4) {  // Whn
    const int r = s - S3;
    const int t = r / (8 * 512);
    const int o = (r / 512) & 7;
    const int pos = r & 511;
    const int l = pos >> 3, j = pos & 7;
    const int n = 512 + t * 16 + (l & 15);
    const float w = Whh[n * HH + o * 32 + (l >> 4) * 8 + j];
    ushort hi = bf16_rne(w);
    ushort lo = bf16_rne(w - bf16_f32(hi));
    g_Whnp[((t * 8 + o) * 2) * 512 + pos] = hi;
    g_Whnp[((t * 8 + o) * 2 + 1) * 512 + pos] = lo;
  } else {  // Win (hi only)
    const int r = s - S4;
    const int t = r / (2 * 512);
    const int o = (r / 512) & 1;
    const int pos = r & 511;
    const int l = pos >> 3, j = pos & 7;
    const int n = 512 + t * 16 + (l & 15);
    const float w = Wih[n * DD + o * 32 + (l >> 4) * 8 + j];
    g_Winp[(t * 2 + o) * 512 + pos] = bf16_rne(w);
  }
}

#define MFMA(A, B, C) __builtin_amdgcn_mfma_f32_16x16x32_bf16((A), (B), (C), 0, 0, 0)

// LDS-only barrier: waits lgkm only (keeps global loads in flight across it)
#define LBAR() asm volatile("s_waitcnt lgkmcnt(0)\ns_barrier" ::: "memory")

// Half-burst liveness fence: 8 quads (32 VGPR) — the largest burst the
// 64-reg budget of a 1024-thread block can fund without spilling (R8: 16-quad
// burst spilled; R6: no burst -> depth-2 serial chains).
__device__ __forceinline__ void sink8(const bf16x8* W, const bf16x8* L) {
  const f32x4 w0 = __builtin_bit_cast(f32x4, W[0]), w1 = __builtin_bit_cast(f32x4, W[1]);
  const f32x4 w2 = __builtin_bit_cast(f32x4, W[2]), w3 = __builtin_bit_cast(f32x4, W[3]);
  const f32x4 l0 = __builtin_bit_cast(f32x4, L[0]), l1 = __builtin_bit_cast(f32x4, L[1]);
  const f32x4 l2 = __builtin_bit_cast(f32x4, L[2]), l3 = __builtin_bit_cast(f32x4, L[3]);
  asm volatile("" :: "v"(w0), "v"(w1), "v"(w2), "v"(w3),
                     "v"(l0), "v"(l1), "v"(l2), "v"(l3));
}
__device__ __forceinline__ void sink2(const bf16x8 a, const bf16x8 b) {
  const f32x4 t0 = __builtin_bit_cast(f32x4, a);
  const f32x4 t1 = __builtin_bit_cast(f32x4, b);
  asm volatile("" :: "v"(t0), "v"(t1));
}

// 1 N-tile, K=256, 3-term split accumulation.
// Two 8-quad half-bursts per tile: load latency paid 2x per tile, not ~8x.
__device__ __forceinline__ f32x4 mm1(const ushort* __restrict__ Ahi,
                                     const ushort* __restrict__ Alo,
                                     const ushort* __restrict__ pack,
                                     int tile, int lane, int aoff, f32x4 acc)
{
  const ushort* wp = pack + (size_t)tile * 8192 + lane * 8;
  f32x4 a0 = acc;
  f32x4 a1 = {0.f, 0.f, 0.f, 0.f};
#pragma unroll
  for (int half = 0; half < 2; ++half) {
    bf16x8 wh[4], wl[4];
#pragma unroll
    for (int o = 0; o < 4; ++o) {
      wh[o] = *(const bf16x8*)(wp + (half * 4 + o) * 1024);
      wl[o] = *(const bf16x8*)(wp + (half * 4 + o) * 1024 + 512);
    }
    sink8(wh, wl);
#pragma unroll
    for (int o = 0; o < 4; ++o) {
      const int oo = half * 4 + o;
      const bf16x8 ah = *(const bf16x8*)(Ahi + aoff + oo * 32);
      const bf16x8 al = *(const bf16x8*)(Alo + aoff + oo * 32);
      f32x4& ac = (o & 1) ? a1 : a0;
      ac = MFMA(ah, wh[o], ac);
      ac = MFMA(al, wh[o], ac);
      ac = MFMA(ah, wl[o], ac);
    }
  }
  return a0 + a1;
}

// One Wrzp tile: K=256 h-part (3-term, two half-bursts) + K=64 x-part (2-term)
__device__ __forceinline__ f32x4 mm_rzt(const ushort* __restrict__ Ahi,
                                        const ushort* __restrict__ Alo,
                                        const ushort* __restrict__ Xhi,
                                        const ushort* __restrict__ Xlo,
                                        int tile, int lane, int aoff, int xoff,
                                        f32x4 acc)
{
  const ushort* p = g_Wrzp + (size_t)tile * 10240 + lane * 8;
  f32x4 a0 = acc;
  f32x4 a1 = {0.f, 0.f, 0.f, 0.f};
#pragma unroll
  for (int half = 0; half < 2; ++half) {
    bf16x8 wh[4], wl[4];
#pragma unroll
    for (int o = 0; o < 4; ++o) {
      wh[o] = *(const bf16x8*)(p + (half * 4 + o) * 1024);
      wl[o] = *(const bf16x8*)(p + (half * 4 + o) * 1024 + 512);
    }
    sink8(wh, wl);
#pragma unroll
    for (int o = 0; o < 4; ++o) {
      const int oo = half * 4 + o;
      const bf16x8 ah = *(const bf16x8*)(Ahi + aoff + oo * 32);
      const bf16x8 al = *(const bf16x8*)(Alo + aoff + oo * 32);
      f32x4& ac = (o & 1) ? a1 : a0;
      ac = MFMA(ah, wh[o], ac);
      ac = MFMA(al, wh[o], ac);
      ac = MFMA(ah, wl[o], ac);
    }
  }
  {
    bf16x8 wx0 = *(const bf16x8*)(p + 8 * 1024);
    bf16x8 wx1 = *(const bf16x8*)(p + 9 * 1024);
    sink2(wx0, wx1);
    {
      const bf16x8 xh = *(const bf16x8*)(Xhi + xoff);
      const bf16x8 xl = *(const bf16x8*)(Xlo + xoff);
      a0 = MFMA(xh, wx0, a0);
      a0 = MFMA(xl, wx0, a0);
    }
    {
      const bf16x8 xh = *(const bf16x8*)(Xhi + xoff + 32);
      const bf16x8 xl = *(const bf16x8*)(Xlo + xoff + 32);
      a1 = MFMA(xh, wx1, a1);
      a1 = MFMA(xl, wx1, a1);
    }
  }
  return a0 + a1;
}

// GRU n-gate x-side: tile wv of Winp, K=64, hi-only weights, 2-term
__device__ __forceinline__ f32x4 mm_in(const ushort* __restrict__ Xhi,
                                       const ushort* __restrict__ Xlo,
                                       int wv, int lane, int xoff, f32x4 acc)
{
  const ushort* pw = g_Winp + (size_t)wv * 1024 + lane * 8;
  bf16x8 w0 = *(const bf16x8*)(pw);
  bf16x8 w1 = *(const bf16x8*)(pw + 512);
  sink2(w0, w1);
  {
    const bf16x8 xh = *(const bf16x8*)(Xhi + xoff);
    const bf16x8 xl = *(const bf16x8*)(Xlo + xoff);
    acc = MFMA(xh, w0, acc);
    acc = MFMA(xl, w0, acc);
  }
  {
    const bf16x8 xh = *(const bf16x8*)(Xhi + xoff + 32);
    const bf16x8 xl = *(const bf16x8*)(Xlo + xoff + 32);
    acc = MFMA(xh, w1, acc);
    acc = MFMA(xl, w1, acc);
  }
  return acc;
}

__global__ __launch_bounds__(NTHR, 4) void odegru_kernel(
    const float* __restrict__ x, const float* __restrict__ times,
    const float* __restrict__ mask,
    const float* __restrict__ b1, const float* __restrict__ b2,
    const float* __restrict__ bih, const float* __restrict__ bhh,
    float* __restrict__ out)
{
  // f32 state
  __shared__ __align__(16) float sAh[BB * SA];    // h (full f32 state)
  __shared__ __align__(16) float sAin[BB * SA];   // h_ode / RK stage input (f32)
  // bf16 hi/lo matmul planes
  __shared__ __align__(16) ushort sAhh[BB * SB], sAhl[BB * SB];
  __shared__ __align__(16) ushort sAinh[BB * SB], sAinl[BB * SB];
  __shared__ __align__(16) ushort sUh[BB * SB], sUl[BB * SB];
  __shared__ __align__(16) ushort sXh[BB * SXB], sXl[BB * SXB];
  __shared__ __align__(16) float sMt[TT_ * BB];   // mask, transposed [t][b]

  const int tid = threadIdx.x;
  const int lane = tid & 63;
  const int wv = tid >> 6;     // wave 0..15, owns output col-tile wv
  const int l15 = lane & 15;
  const int lq = lane >> 4;    // 0..3
  const int b0 = blockIdx.x * BB;
  const int aoff = l15 * SB + lq * 8;
  const int xoff = l15 * SXB + lq * 8;

  const int c = wv * 16 + l15;       // this thread's output column
  const float b1c = b1[c];
  const float b2c = b2[c];
  const float brz_r = bih[c] + bhh[c];
  const float brz_z = bih[c + 256] + bhh[c + 256];
  const float bn_i = bih[c + 512];
  const float bn_h = bhh[c + 512];

  const f32x4 Z = {0.f, 0.f, 0.f, 0.f};

  // stage mask transposed: sMt[t][b]  (conflict-free broadcast reads later)
  {
    const int e0 = tid, e1 = tid + 1024;
    sMt[(e0 & 127) * BB + (e0 >> 7)] = mask[(size_t)(b0 + (e0 >> 7)) * TT_ + (e0 & 127)];
    sMt[(e1 & 127) * BB + (e1 >> 7)] = mask[(size_t)(b0 + (e1 >> 7)) * TT_ + (e1 & 127)];
  }

  // feval: A-planes -> kv (per-thread: col c, batches lq*4+q)
  auto feval = [&](const ushort* Ahi, const ushort* Alo, f32x4& kv) {
    f32x4 a = mm1(Ahi, Alo, g_W1p, wv, lane, aoff, Z);
#pragma unroll
    for (int q = 0; q < 4; ++q) {
      const int b = lq * 4 + q;
      const float u = fmaxf(a[q] + b1c, 0.f);
      ushort hi, lo; hl_split(u, hi, lo);
      sUh[b * SB + c] = hi;
      sUl[b * SB + c] = lo;
    }
    LBAR();
    f32x4 p = mm1(sUh, sUl, g_W2p, wv, lane, aoff, Z);
    kv = p + b2c;
  };

  // sAin <- sAh + coef*v (f32) and refresh Ain planes
  auto wAin = [&](float coef, const f32x4& v) {
#pragma unroll
    for (int q = 0; q < 4; ++q) {
      const int b = lq * 4 + q;
      const float nv = sAh[b * SA + c] + coef * v[q];
      sAin[b * SA + c] = nv;
      ushort hi, lo; hl_split(nv, hi, lo);
      sAinh[b * SB + c] = hi;
      sAinl[b * SB + c] = lo;
    }
  };

  for (int t = 0; t < TT_; ++t) {
    // stage x[:, t, :] as hi/lo planes
    {
      const int b = tid >> 6, d = tid & 63;
      const float v = x[((size_t)(b0 + b) * TT_ + t) * DD + d];
      ushort hi, lo; hl_split(v, hi, lo);
      sXh[b * SXB + d] = hi;
      sXl[b * SXB + d] = lo;
    }
    if (t == 0) {
      const int cc = tid & 255;
#pragma unroll
      for (int q = 0; q < 4; ++q) {
        const int b = (tid >> 8) * 4 + q;
        sAin[b * SA + cc] = 0.f;
        sAinh[b * SB + cc] = 0;
        sAinl[b * SB + cc] = 0;
      }
    }
    LBAR();

    if (t > 0) {
      const float dtv = times[t] - times[t - 1];
      f32x4 kv, ks;
      // k1 (reads h planes)
      feval(sAhh, sAhl, kv);
      ks = kv;
      wAin(0.5f * dtv, kv);
      LBAR();
      // k2
      feval(sAinh, sAinl, kv);
      ks += 2.0f * kv;
      wAin(0.5f * dtv, kv);
      LBAR();
      // k3
      feval(sAinh, sAinl, kv);
      ks += 2.0f * kv;
      wAin(dtv, kv);
      LBAR();
      // k4
      feval(sAinh, sAinl, kv);
      ks += kv;
      wAin(dtv * (1.0f / 6.0f), ks);  // sAin <- h_ode
      LBAR();
    }

    // ---- GRU: this wave computes r,z,hn,in for its 16 cols, all 16 batches ----
    {
      f32x4 ar = mm_rzt(sAinh, sAinl, sXh, sXl, wv, lane, aoff, xoff, Z);
      f32x4 az = mm_rzt(sAinh, sAinl, sXh, sXl, 16 + wv, lane, aoff, xoff, Z);
      f32x4 ahn = mm1(sAinh, sAinl, g_Whnp, wv, lane, aoff, Z);
      f32x4 ain = mm_in(sXh, sXl, wv, lane, xoff, Z);

#pragma unroll
      for (int q = 0; q < 4; ++q) {
        const int b = lq * 4 + q;
        const float gr = ar[q] + brz_r;
        const float gz = az[q] + brz_z;
        const float hn = ahn[q] + bn_h;
        const float gn = ain[q] + bn_i;
        const float hode = sAin[b * SA + c];
        const float rg = 1.f / (1.f + __expf(-gr));
        const float zg = 1.f / (1.f + __expf(-gz));
        const float ng = 1.f - 2.f / (__expf(2.f * (gn + rg * hn)) + 1.f);
        const float hnext = (1.f - zg) * ng + zg * hode;
        const float m = sMt[t * BB + b];
        const float hnew = m * hnext + (1.f - m) * hode;
        // NT store: out is never re-read; don't let the stream allocate in L2
        __builtin_nontemporal_store(hnew, &out[((size_t)(b0 + b) * TT_ + t) * HH + c]);
        sAh[b * SA + c] = hnew;
        ushort hi, lo; hl_split(hnew, hi, lo);
        sAhh[b * SB + c] = hi;
        sAhl[b * SB + c] = lo;
      }
    }
    LBAR();
  }
}

extern "C" void kernel_launch(void* const* d_in, const int* in_sizes, int n_in,
                              void* d_out, int out_size, void* d_ws, size_t ws_size,
                              hipStream_t stream) {
  (void)in_sizes; (void)n_in; (void)d_ws; (void)ws_size; (void)out_size;
  const float* x     = (const float*)d_in[0];
  const float* times = (const float*)d_in[1];
  const float* mask  = (const float*)d_in[2];
  const float* W1    = (const float*)d_in[3];
  const float* b1    = (const float*)d_in[4];
  const float* W2    = (const float*)d_in[5];
  const float* b2    = (const float*)d_in[6];
  const float* Wih   = (const float*)d_in[7];
  const float* bih   = (const float*)d_in[8];
  const float* Whh   = (const float*)d_in[9];
  const float* bhh   = (const float*)d_in[10];
  float* out = (float*)d_out;

  hipLaunchKernelGGL(prep, dim3((376832 + 255) / 256), dim3(256), 0, stream,
                     W1, W2, Wih, Whh);
  hipLaunchKernelGGL(odegru_kernel, dim3(NBLK), dim3(NTHR), 0, stream,
                     x, times, mask, b1, b2, bih, bhh, out);
}